// Round 11
// baseline (280.773 us; speedup 1.0000x reference)
//
#include <hip/hip_runtime.h>
#include <hip/hip_bf16.h>

typedef _Float16 f16;
typedef _Float16 f16x2 __attribute__((ext_vector_type(2)));
typedef _Float16 f16x4 __attribute__((ext_vector_type(4)));
typedef _Float16 f16x8 __attribute__((ext_vector_type(8)));
typedef __fp16 h16x2 __attribute__((ext_vector_type(2)));
typedef float f32x4 __attribute__((ext_vector_type(4)));

// Problem constants
#define NHEADS 6
#define NTOK 256
#define NWINS 256
#define DIM 192
#define HD 32
#define C3 576
#define LOG2E 1.4426950408889634f
#define SCALE (0.17677669529663687f * LOG2E)

__device__ inline f16x2 pkrtz(float a, float b) {
  h16x2 r = __builtin_amdgcn_cvt_pkrtz(a, b);
  return __builtin_bit_cast(f16x2, r);
}

// ---------------------------------------------------------------------------
// Kernel 1: CB[mg][h][q][k] = (rpb[rpi]+mask)*log2e  (f32; seeds MFMA C)
// ---------------------------------------------------------------------------
__global__ __launch_bounds__(256) void prep_cb_kernel(const int* __restrict__ rpi,
                                                      const float* __restrict__ mask,
                                                      const float* __restrict__ rpb,
                                                      float* __restrict__ cb) {
  int idx = blockIdx.x * 256 + threadIdx.x;
  int k = idx & 255;
  int q = (idx >> 8) & 255;
  int t = idx >> 16;
  int h = t % 6;
  int mg = t / 6;
  cb[idx] = (rpb[rpi[(q << 8) | k] * 6 + h] + mask[(mg << 16) | (q << 8) | k]) * LOG2E;
}

__global__ __launch_bounds__(256) void prep_w_kernel(const float* __restrict__ w,
                                                     f16* __restrict__ w16) {
  int i = blockIdx.x * 256 + threadIdx.x;
  if (i < DIM * DIM) w16[i] = (f16)w[i];
}

__device__ inline f16x8 q_to_f16(float4 a, float4 b) {
  f16x2 p0 = pkrtz(a.x * SCALE, a.y * SCALE);
  f16x2 p1 = pkrtz(a.z * SCALE, a.w * SCALE);
  f16x2 p2 = pkrtz(b.x * SCALE, b.y * SCALE);
  f16x2 p3 = pkrtz(b.z * SCALE, b.w * SCALE);
  f16x4 lo = __builtin_shufflevector(p0, p1, 0, 1, 2, 3);
  f16x4 hi = __builtin_shufflevector(p2, p3, 0, 1, 2, 3);
  return __builtin_shufflevector(lo, hi, 0, 1, 2, 3, 4, 5, 6, 7);
}

// ---------------------------------------------------------------------------
// Kernel 3: fused window attention — ABLATION TEMPLATE (r11).
// VAR=0 full (real output, launched LAST among attn variants)
// VAR=1 no cb bias loads (acc seeded 0)      -> marginal cost of bias table
// VAR=2 no softmax (P = raw scores, rinv=1)  -> marginal cost of softmax chain
// VAR=3 no PV (store f(m,s))                 -> marginal cost of PV MFMA+LDS
// Probes write into the same x16 buffer; V0 overwrites everything after.
// ---------------------------------------------------------------------------
template<int VAR>
__global__ __launch_bounds__(512, 4) void attn_kernel(const float* __restrict__ qkv,
                                                      const float* __restrict__ cb,
                                                      f16* __restrict__ x16) {
  const int idx = blockIdx.x;
  const int b = idx & 255;
  const int h = idx >> 8;
  const int tid = threadIdx.x;
  const int lane = tid & 63;
  const int wave = tid >> 6;
  const int g = lane >> 4;
  const int r16 = lane & 15;

  __shared__ f16 Klin[16 * 64 * 8];
  __shared__ f16 VT[32][264];

  // ---- stage K (waves 0-3) / V (waves 4-7) ----
  {
    const int t = tid & 255;
    const int srow = t >> 3;
    const int part = t & 7;
    const bool isK = tid < 256;
    const float* base = qkv + (size_t)(b * NTOK + srow) * C3 + DIM + (isK ? 0 : DIM)
                        + h * HD + part * 4;
    const int gg = part >> 1;
    const int half = part & 1;
    const int d0 = part * 4;
#pragma unroll
    for (int batch = 0; batch < 2; ++batch) {
      float4 v4[4];
#pragma unroll
      for (int rg = 0; rg < 4; ++rg)
        v4[rg] = *(const float4*)(base + (size_t)((batch * 4 + rg) * 32) * C3);
#pragma unroll
      for (int rg = 0; rg < 4; ++rg) {
        const int row = (batch * 4 + rg) * 32 + srow;
        if (isK) {
          const int slot = ((row >> 4) * 64) + gg * 16 + ((row & 15) ^ (gg << 2));
          f16x2 k01 = pkrtz(v4[rg].x, v4[rg].y);
          f16x2 k23 = pkrtz(v4[rg].z, v4[rg].w);
          *((f16x4*)&Klin[slot * 8 + half * 4]) =
              __builtin_shufflevector(k01, k23, 0, 1, 2, 3);
        } else {
          VT[d0 + 0][row ^ (((d0 + 0) & 7) << 2)] = (f16)v4[rg].x;
          VT[d0 + 1][row ^ (((d0 + 1) & 7) << 2)] = (f16)v4[rg].y;
          VT[d0 + 2][row ^ (((d0 + 2) & 7) << 2)] = (f16)v4[rg].z;
          VT[d0 + 3][row ^ (((d0 + 3) & 7) << 2)] = (f16)v4[rg].w;
        }
      }
    }
  }
  __syncthreads();

  const int qbase = wave * 32;
  const float* cbb = cb + (((size_t)((b & 15) * 6 + h)) << 16);
  const int krd = (lane & 48) + ((lane & 15) ^ ((lane >> 2) & 12));

#pragma unroll
  for (int c = 0; c < 2; ++c) {
    const int qrow = qbase + c * 16 + r16;
    const float* qp = qkv + (size_t)(b * NTOK + qrow) * C3 + h * HD + g * 8;
    f16x8 qf = q_to_f16(((const float4*)qp)[0], ((const float4*)qp)[1]);
    const float* cbq = cbb + ((size_t)qrow << 8) + g * 4;

    // ================= phase A: keys 0..127 =================
    f32x4 acc[8];
#pragma unroll
    for (int kt = 0; kt < 8; ++kt) {
      if constexpr (VAR == 1) {
        acc[kt][0] = 0.f; acc[kt][1] = 0.f; acc[kt][2] = 0.f; acc[kt][3] = 0.f;
      } else {
        acc[kt] = *((const f32x4*)(cbq + kt * 16));
      }
    }
#pragma unroll
    for (int kt = 0; kt < 8; ++kt) {
      f16x8 af = *((const f16x8*)&Klin[(kt * 64 + krd) * 8]);
      acc[kt] = __builtin_amdgcn_mfma_f32_16x16x32_f16(af, qf, acc[kt], 0, 0, 0);
    }

    float mA = 0.f, sA = 0.f;
    if constexpr (VAR != 2) {
      float m0 = fmaxf(fmaxf(acc[0][0], acc[1][0]), fmaxf(acc[2][0], acc[3][0]));
      float m1 = fmaxf(fmaxf(acc[0][1], acc[1][1]), fmaxf(acc[2][1], acc[3][1]));
      float m2 = fmaxf(fmaxf(acc[0][2], acc[1][2]), fmaxf(acc[2][2], acc[3][2]));
      float m3 = fmaxf(fmaxf(acc[0][3], acc[1][3]), fmaxf(acc[2][3], acc[3][3]));
#pragma unroll
      for (int kt = 4; kt < 8; ++kt) {
        m0 = fmaxf(m0, acc[kt][0]); m1 = fmaxf(m1, acc[kt][1]);
        m2 = fmaxf(m2, acc[kt][2]); m3 = fmaxf(m3, acc[kt][3]);
      }
      mA = fmaxf(fmaxf(m0, m1), fmaxf(m2, m3));
      mA = fmaxf(mA, __shfl_xor(mA, 16));
      mA = fmaxf(mA, __shfl_xor(mA, 32));

      float s0 = 0.f, s1 = 0.f, s2 = 0.f, s3 = 0.f;
#pragma unroll
      for (int kt = 0; kt < 8; ++kt) {
        float p0 = __builtin_amdgcn_exp2f(acc[kt][0] - mA);
        float p1 = __builtin_amdgcn_exp2f(acc[kt][1] - mA);
        float p2 = __builtin_amdgcn_exp2f(acc[kt][2] - mA);
        float p3 = __builtin_amdgcn_exp2f(acc[kt][3] - mA);
        acc[kt][0] = p0; acc[kt][1] = p1; acc[kt][2] = p2; acc[kt][3] = p3;
        s0 += p0; s1 += p1; s2 += p2; s3 += p3;
      }
      sA = (s0 + s1) + (s2 + s3);
    }

    // PV phase A — 2 chains per dt
    f32x4 xa0[2], xa1[2];
#pragma unroll
    for (int dt = 0; dt < 2; ++dt) {
      xa0[dt][0] = 0.f; xa0[dt][1] = 0.f; xa0[dt][2] = 0.f; xa0[dt][3] = 0.f;
      xa1[dt][0] = 0.f; xa1[dt][1] = 0.f; xa1[dt][2] = 0.f; xa1[dt][3] = 0.f;
    }
    if constexpr (VAR != 3) {
#pragma unroll
      for (int kt = 0; kt < 8; ++kt) {
        f16x2 p01 = pkrtz(acc[kt][0], acc[kt][1]);
        f16x2 p23 = pkrtz(acc[kt][2], acc[kt][3]);
        f16x4 pf = __builtin_shufflevector(p01, p23, 0, 1, 2, 3);
#pragma unroll
        for (int dt = 0; dt < 2; ++dt) {
          const int col = (kt * 16 + g * 4) ^ ((r16 & 7) << 2);
          f16x4 vf = *((const f16x4*)&VT[dt * 16 + r16][col]);
          if (kt < 4)
            xa0[dt] = __builtin_amdgcn_mfma_f32_16x16x16f16(vf, pf, xa0[dt], 0, 0, 0);
          else
            xa1[dt] = __builtin_amdgcn_mfma_f32_16x16x16f16(vf, pf, xa1[dt], 0, 0, 0);
        }
      }
    }

    // ================= phase B: keys 128..255 =================
#pragma unroll
    for (int kt = 0; kt < 8; ++kt) {
      if constexpr (VAR == 1) {
        acc[kt][0] = 0.f; acc[kt][1] = 0.f; acc[kt][2] = 0.f; acc[kt][3] = 0.f;
      } else {
        acc[kt] = *((const f32x4*)(cbq + 128 + kt * 16));
      }
    }
#pragma unroll
    for (int kt = 0; kt < 8; ++kt) {
      f16x8 af = *((const f16x8*)&Klin[((kt + 8) * 64 + krd) * 8]);
      acc[kt] = __builtin_amdgcn_mfma_f32_16x16x32_f16(af, qf, acc[kt], 0, 0, 0);
    }

    float rinv = 1.0f, scA = 1.0f, m = 0.f, s = 0.f;
    if constexpr (VAR != 2) {
      float m0 = fmaxf(fmaxf(acc[0][0], acc[1][0]), fmaxf(acc[2][0], acc[3][0]));
      float m1 = fmaxf(fmaxf(acc[0][1], acc[1][1]), fmaxf(acc[2][1], acc[3][1]));
      float m2 = fmaxf(fmaxf(acc[0][2], acc[1][2]), fmaxf(acc[2][2], acc[3][2]));
      float m3 = fmaxf(fmaxf(acc[0][3], acc[1][3]), fmaxf(acc[2][3], acc[3][3]));
#pragma unroll
      for (int kt = 4; kt < 8; ++kt) {
        m0 = fmaxf(m0, acc[kt][0]); m1 = fmaxf(m1, acc[kt][1]);
        m2 = fmaxf(m2, acc[kt][2]); m3 = fmaxf(m3, acc[kt][3]);
      }
      float mB = fmaxf(fmaxf(m0, m1), fmaxf(m2, m3));
      mB = fmaxf(mB, __shfl_xor(mB, 16));
      mB = fmaxf(mB, __shfl_xor(mB, 32));

      m = fmaxf(mA, mB);
      scA = __builtin_amdgcn_exp2f(mA - m);

      float s0 = 0.f, s1 = 0.f, s2 = 0.f, s3 = 0.f;
#pragma unroll
      for (int kt = 0; kt < 8; ++kt) {
        float p0 = __builtin_amdgcn_exp2f(acc[kt][0] - m);
        float p1 = __builtin_amdgcn_exp2f(acc[kt][1] - m);
        float p2 = __builtin_amdgcn_exp2f(acc[kt][2] - m);
        float p3 = __builtin_amdgcn_exp2f(acc[kt][3] - m);
        acc[kt][0] = p0; acc[kt][1] = p1; acc[kt][2] = p2; acc[kt][3] = p3;
        s0 += p0; s1 += p1; s2 += p2; s3 += p3;
      }
      s = sA * scA + (s0 + s1) + (s2 + s3);
      s += __shfl_xor(s, 16);
      s += __shfl_xor(s, 32);
      rinv = 1.0f / s;
    }

    f16* xp = x16 + (size_t)(b * NTOK + qrow) * DIM + h * HD;

    if constexpr (VAR == 3) {
      // PV skipped: store f(m, s) so QK+softmax stay live
      float val = (m + s) * rinv;
      f16x2 o = pkrtz(val, val);
#pragma unroll
      for (int dt = 0; dt < 2; ++dt) {
        *((f16x4*)(xp + dt * 16 + g * 4)) = __builtin_shufflevector(o, o, 0, 1, 2, 3);
      }
    } else {
      if constexpr (VAR != 2) {
#pragma unroll
        for (int dt = 0; dt < 2; ++dt) {
          xa0[dt][0] *= scA; xa0[dt][1] *= scA; xa0[dt][2] *= scA; xa0[dt][3] *= scA;
          xa1[dt][0] *= scA; xa1[dt][1] *= scA; xa1[dt][2] *= scA; xa1[dt][3] *= scA;
        }
      }
#pragma unroll
      for (int kt = 0; kt < 8; ++kt) {
        f16x2 p01 = pkrtz(acc[kt][0], acc[kt][1]);
        f16x2 p23 = pkrtz(acc[kt][2], acc[kt][3]);
        f16x4 pf = __builtin_shufflevector(p01, p23, 0, 1, 2, 3);
#pragma unroll
        for (int dt = 0; dt < 2; ++dt) {
          const int col = ((kt + 8) * 16 + g * 4) ^ ((r16 & 7) << 2);
          f16x4 vf = *((const f16x4*)&VT[dt * 16 + r16][col]);
          if (kt < 4)
            xa0[dt] = __builtin_amdgcn_mfma_f32_16x16x16f16(vf, pf, xa0[dt], 0, 0, 0);
          else
            xa1[dt] = __builtin_amdgcn_mfma_f32_16x16x16f16(vf, pf, xa1[dt], 0, 0, 0);
        }
      }
#pragma unroll
      for (int dt = 0; dt < 2; ++dt) {
        f16x2 o01 = pkrtz((xa0[dt][0] + xa1[dt][0]) * rinv,
                          (xa0[dt][1] + xa1[dt][1]) * rinv);
        f16x2 o23 = pkrtz((xa0[dt][2] + xa1[dt][2]) * rinv,
                          (xa0[dt][3] + xa1[dt][3]) * rinv);
        *((f16x4*)(xp + dt * 16 + g * 4)) = __builtin_shufflevector(o01, o23, 0, 1, 2, 3);
      }
    }
  }
}

// ---------------------------------------------------------------------------
// Kernel 4: out = X16 @ W16^T + pb
// ---------------------------------------------------------------------------
__global__ __launch_bounds__(256) void proj_kernel(const f16* __restrict__ x16,
                                                   const f16* __restrict__ w16,
                                                   const float* __restrict__ pb,
                                                   float* __restrict__ out) {
  const int lane = threadIdx.x & 63;
  const int wave = threadIdx.x >> 6;
  const int g = lane >> 4;
  const int r16 = lane & 15;
  const int m0 = blockIdx.x * 64 + wave * 16;

  f32x4 acc[12];
#pragma unroll
  for (int jt = 0; jt < 12; ++jt) {
    acc[jt][0] = 0.f; acc[jt][1] = 0.f; acc[jt][2] = 0.f; acc[jt][3] = 0.f;
  }
#pragma unroll
  for (int cc = 0; cc < 6; ++cc) {
    f16x8 af = *((const f16x8*)(x16 + (size_t)(m0 + r16) * DIM + cc * 32 + g * 8));
#pragma unroll
    for (int jt = 0; jt < 12; ++jt) {
      f16x8 bf = *((const f16x8*)(w16 + (size_t)(jt * 16 + r16) * DIM + cc * 32 + g * 8));
      acc[jt] = __builtin_amdgcn_mfma_f32_16x16x32_f16(af, bf, acc[jt], 0, 0, 0);
    }
  }
#pragma unroll
  for (int jt = 0; jt < 12; ++jt) {
    int j = jt * 16 + r16;
    float bias = pb[j];
#pragma unroll
    for (int r = 0; r < 4; ++r) {
      out[(size_t)(m0 + g * 4 + r) * DIM + j] = acc[jt][r] + bias;
    }
  }
}

// ---------------------------------------------------------------------------
extern "C" void kernel_launch(void* const* d_in, const int* in_sizes, int n_in,
                              void* d_out, int out_size, void* d_ws, size_t ws_size,
                              hipStream_t stream) {
  const float* qkv  = (const float*)d_in[0];
  const int*   rpi  = (const int*)d_in[1];
  const float* mask = (const float*)d_in[2];
  const float* rpb  = (const float*)d_in[3];
  const float* pw   = (const float*)d_in[4];
  const float* pbv  = (const float*)d_in[5];
  float* out = (float*)d_out;

  char* ws = (char*)d_ws;
  float* cb = (float*)ws;                            // 25,165,824 B
  f16* x16  = (f16*)(ws + 25165824);                 // 25,165,824 B
  f16* w16  = (f16*)(ws + 25165824 + 25165824);      // 73,728 B

  prep_cb_kernel<<<24576, 256, 0, stream>>>(rpi, mask, rpb, cb);
  prep_w_kernel<<<144, 256, 0, stream>>>(pw, w16);
  // ---- ablation probes (write x16, fully overwritten by V0 below) ----
  attn_kernel<1><<<1536, 512, 0, stream>>>(qkv, cb, x16);  // no cb loads
  attn_kernel<3><<<1536, 512, 0, stream>>>(qkv, cb, x16);  // no PV
  attn_kernel<2><<<1536, 512, 0, stream>>>(qkv, cb, x16);  // no softmax
  // ---- real kernel (last attn writer) ----
  attn_kernel<0><<<1536, 512, 0, stream>>>(qkv, cb, x16);
  proj_kernel<<<1024, 256, 0, stream>>>(x16, w16, pbv, out);
}

// Round 12
// 158.240 us; speedup vs baseline: 1.7744x; 1.7744x over previous
//
#include <hip/hip_runtime.h>
#include <hip/hip_bf16.h>

typedef _Float16 f16;
typedef _Float16 f16x2 __attribute__((ext_vector_type(2)));
typedef _Float16 f16x4 __attribute__((ext_vector_type(4)));
typedef _Float16 f16x8 __attribute__((ext_vector_type(8)));
typedef __fp16 h16x2 __attribute__((ext_vector_type(2)));
typedef float f32x4 __attribute__((ext_vector_type(4)));

// Problem constants
#define NHEADS 6
#define NTOK 256
#define NWINS 256
#define DIM 192
#define HD 32
#define C3 576
#define LOG2E 1.4426950408889634f
#define SCALE (0.17677669529663687f * LOG2E)

__device__ inline f16x2 pkrtz(float a, float b) {
  h16x2 r = __builtin_amdgcn_cvt_pkrtz(a, b);
  return __builtin_bit_cast(f16x2, r);
}

// ---------------------------------------------------------------------------
// Kernel 1a: rpb16[h][q][k] = rpb[rpi[q,k], h] * log2e   (6*64K f16 = 786 KB)
// Unique size fits per-XCD L2 -> attn bias loads become L2 hits.
// ---------------------------------------------------------------------------
__global__ __launch_bounds__(256) void prep_rpb_kernel(const int* __restrict__ rpi,
                                                       const float* __restrict__ rpb,
                                                       f16* __restrict__ rpb16) {
  int idx = blockIdx.x * 256 + threadIdx.x;   // h*65536 + q*256 + k
  int qk = idx & 65535;
  int h = idx >> 16;
  rpb16[idx] = (f16)(rpb[rpi[qk] * 6 + h] * LOG2E);
}

// ---------------------------------------------------------------------------
// Kernel 1b: mask16[mg][q][k] = mask[mg][q][k] * log2e   (16*64K f16 = 2 MB)
// ---------------------------------------------------------------------------
__global__ __launch_bounds__(256) void prep_mask_kernel(const float* __restrict__ mask,
                                                        f16* __restrict__ mask16) {
  int i = (blockIdx.x * 256 + threadIdx.x) * 4;
  float4 v = *(const float4*)(mask + i);
  f16x2 lo = pkrtz(v.x * LOG2E, v.y * LOG2E);
  f16x2 hi = pkrtz(v.z * LOG2E, v.w * LOG2E);
  *((f16x4*)(mask16 + i)) = __builtin_shufflevector(lo, hi, 0, 1, 2, 3);
}

// ---------------------------------------------------------------------------
// Kernel 2: W (192x192) fp32 -> f16
// ---------------------------------------------------------------------------
__global__ __launch_bounds__(256) void prep_w_kernel(const float* __restrict__ w,
                                                     f16* __restrict__ w16) {
  int i = blockIdx.x * 256 + threadIdx.x;
  if (i < DIM * DIM) w16[i] = (f16)w[i];
}

__device__ inline f16x8 q_to_f16(float4 a, float4 b) {
  f16x2 p0 = pkrtz(a.x * SCALE, a.y * SCALE);
  f16x2 p1 = pkrtz(a.z * SCALE, a.w * SCALE);
  f16x2 p2 = pkrtz(b.x * SCALE, b.y * SCALE);
  f16x2 p3 = pkrtz(b.z * SCALE, b.w * SCALE);
  f16x4 lo = __builtin_shufflevector(p0, p1, 0, 1, 2, 3);
  f16x4 hi = __builtin_shufflevector(p2, p3, 0, 1, 2, 3);
  return __builtin_shufflevector(lo, hi, 0, 1, 2, 3, 4, 5, 6, 7);
}

// ---------------------------------------------------------------------------
// Kernel 3: fused window attention. Block = (b, h). 512 thr = 8 waves.
// r12: bias split into rpb16[h] + mask16[b&15] (2.8 MB unique total ->
// L2-resident on every XCD; r8-r11 cb was 12-25 MB -> L3-served, ~400 MB
// logical traffic = the invariant 97 us). Loads issued before QK MFMAs,
// packed-f16 add after. Otherwise r10 structure: (512,4), online softmax
// over 2 k-halves, PV dual chains, K/V staged once.
// ---------------------------------------------------------------------------
__global__ __launch_bounds__(512, 4) void attn_kernel(const float* __restrict__ qkv,
                                                      const f16* __restrict__ rpb16,
                                                      const f16* __restrict__ mask16,
                                                      f16* __restrict__ x16) {
  const int idx = blockIdx.x;
  const int b = idx & 255;
  const int h = idx >> 8;
  const int tid = threadIdx.x;
  const int lane = tid & 63;
  const int wave = tid >> 6;
  const int g = lane >> 4;
  const int r16 = lane & 15;

  __shared__ f16 Klin[16 * 64 * 8];
  __shared__ f16 VT[32][264];

  // ---- stage K (waves 0-3) / V (waves 4-7) ----
  {
    const int t = tid & 255;
    const int srow = t >> 3;
    const int part = t & 7;
    const bool isK = tid < 256;
    const float* base = qkv + (size_t)(b * NTOK + srow) * C3 + DIM + (isK ? 0 : DIM)
                        + h * HD + part * 4;
    const int gg = part >> 1;
    const int half = part & 1;
    const int d0 = part * 4;
#pragma unroll
    for (int batch = 0; batch < 2; ++batch) {
      float4 v4[4];
#pragma unroll
      for (int rg = 0; rg < 4; ++rg)
        v4[rg] = *(const float4*)(base + (size_t)((batch * 4 + rg) * 32) * C3);
#pragma unroll
      for (int rg = 0; rg < 4; ++rg) {
        const int row = (batch * 4 + rg) * 32 + srow;
        if (isK) {
          const int slot = ((row >> 4) * 64) + gg * 16 + ((row & 15) ^ (gg << 2));
          f16x2 k01 = pkrtz(v4[rg].x, v4[rg].y);
          f16x2 k23 = pkrtz(v4[rg].z, v4[rg].w);
          *((f16x4*)&Klin[slot * 8 + half * 4]) =
              __builtin_shufflevector(k01, k23, 0, 1, 2, 3);
        } else {
          VT[d0 + 0][row ^ (((d0 + 0) & 7) << 2)] = (f16)v4[rg].x;
          VT[d0 + 1][row ^ (((d0 + 1) & 7) << 2)] = (f16)v4[rg].y;
          VT[d0 + 2][row ^ (((d0 + 2) & 7) << 2)] = (f16)v4[rg].z;
          VT[d0 + 3][row ^ (((d0 + 3) & 7) << 2)] = (f16)v4[rg].w;
        }
      }
    }
  }
  __syncthreads();

  const int qbase = wave * 32;
  const f16* rb = rpb16 + ((size_t)h << 16);
  const f16* mb = mask16 + ((size_t)(b & 15) << 16);
  const int krd = (lane & 48) + ((lane & 15) ^ ((lane >> 2) & 12));

#pragma unroll
  for (int c = 0; c < 2; ++c) {
    const int qrow = qbase + c * 16 + r16;
    const float* qp = qkv + (size_t)(b * NTOK + qrow) * C3 + h * HD + g * 8;
    f16x8 qf = q_to_f16(((const float4*)qp)[0], ((const float4*)qp)[1]);
    const int qoff = (qrow << 8) + g * 4;

    // ================= phase A: keys 0..127 =================
    // issue bias loads first (L2-resident; hidden under the 8 MFMAs)
    f16x4 rv[8], mv[8];
#pragma unroll
    for (int kt = 0; kt < 8; ++kt) {
      rv[kt] = *((const f16x4*)(rb + qoff + kt * 16));
      mv[kt] = *((const f16x4*)(mb + qoff + kt * 16));
    }
    f32x4 acc[8];
#pragma unroll
    for (int kt = 0; kt < 8; ++kt) {
      acc[kt][0] = 0.f; acc[kt][1] = 0.f; acc[kt][2] = 0.f; acc[kt][3] = 0.f;
    }
#pragma unroll
    for (int kt = 0; kt < 8; ++kt) {
      f16x8 af = *((const f16x8*)&Klin[(kt * 64 + krd) * 8]);
      acc[kt] = __builtin_amdgcn_mfma_f32_16x16x32_f16(af, qf, acc[kt], 0, 0, 0);
    }

    // packed-f16 bias add + 4-chain max
    float m0 = -1e30f, m1 = -1e30f, m2 = -1e30f, m3 = -1e30f;
#pragma unroll
    for (int kt = 0; kt < 8; ++kt) {
      f16x4 sv = rv[kt] + mv[kt];
      acc[kt][0] += (float)sv[0];
      acc[kt][1] += (float)sv[1];
      acc[kt][2] += (float)sv[2];
      acc[kt][3] += (float)sv[3];
      m0 = fmaxf(m0, acc[kt][0]); m1 = fmaxf(m1, acc[kt][1]);
      m2 = fmaxf(m2, acc[kt][2]); m3 = fmaxf(m3, acc[kt][3]);
    }
    float mA = fmaxf(fmaxf(m0, m1), fmaxf(m2, m3));
    mA = fmaxf(mA, __shfl_xor(mA, 16));
    mA = fmaxf(mA, __shfl_xor(mA, 32));

    float s0 = 0.f, s1 = 0.f, s2 = 0.f, s3 = 0.f;
#pragma unroll
    for (int kt = 0; kt < 8; ++kt) {
      float p0 = __builtin_amdgcn_exp2f(acc[kt][0] - mA);
      float p1 = __builtin_amdgcn_exp2f(acc[kt][1] - mA);
      float p2 = __builtin_amdgcn_exp2f(acc[kt][2] - mA);
      float p3 = __builtin_amdgcn_exp2f(acc[kt][3] - mA);
      acc[kt][0] = p0; acc[kt][1] = p1; acc[kt][2] = p2; acc[kt][3] = p3;
      s0 += p0; s1 += p1; s2 += p2; s3 += p3;
    }
    float sA = (s0 + s1) + (s2 + s3);

    // PV phase A — 2 chains per dt
    f32x4 xa0[2], xa1[2];
#pragma unroll
    for (int dt = 0; dt < 2; ++dt) {
      xa0[dt][0] = 0.f; xa0[dt][1] = 0.f; xa0[dt][2] = 0.f; xa0[dt][3] = 0.f;
      xa1[dt][0] = 0.f; xa1[dt][1] = 0.f; xa1[dt][2] = 0.f; xa1[dt][3] = 0.f;
    }
#pragma unroll
    for (int kt = 0; kt < 8; ++kt) {
      f16x2 p01 = pkrtz(acc[kt][0], acc[kt][1]);
      f16x2 p23 = pkrtz(acc[kt][2], acc[kt][3]);
      f16x4 pf = __builtin_shufflevector(p01, p23, 0, 1, 2, 3);
#pragma unroll
      for (int dt = 0; dt < 2; ++dt) {
        const int col = (kt * 16 + g * 4) ^ ((r16 & 7) << 2);
        f16x4 vf = *((const f16x4*)&VT[dt * 16 + r16][col]);
        if (kt < 4)
          xa0[dt] = __builtin_amdgcn_mfma_f32_16x16x16f16(vf, pf, xa0[dt], 0, 0, 0);
        else
          xa1[dt] = __builtin_amdgcn_mfma_f32_16x16x16f16(vf, pf, xa1[dt], 0, 0, 0);
      }
    }

    // ================= phase B: keys 128..255 =================
#pragma unroll
    for (int kt = 0; kt < 8; ++kt) {
      rv[kt] = *((const f16x4*)(rb + qoff + 128 + kt * 16));
      mv[kt] = *((const f16x4*)(mb + qoff + 128 + kt * 16));
    }
#pragma unroll
    for (int kt = 0; kt < 8; ++kt) {
      acc[kt][0] = 0.f; acc[kt][1] = 0.f; acc[kt][2] = 0.f; acc[kt][3] = 0.f;
    }
#pragma unroll
    for (int kt = 0; kt < 8; ++kt) {
      f16x8 af = *((const f16x8*)&Klin[((kt + 8) * 64 + krd) * 8]);
      acc[kt] = __builtin_amdgcn_mfma_f32_16x16x32_f16(af, qf, acc[kt], 0, 0, 0);
    }

    m0 = -1e30f; m1 = -1e30f; m2 = -1e30f; m3 = -1e30f;
#pragma unroll
    for (int kt = 0; kt < 8; ++kt) {
      f16x4 sv = rv[kt] + mv[kt];
      acc[kt][0] += (float)sv[0];
      acc[kt][1] += (float)sv[1];
      acc[kt][2] += (float)sv[2];
      acc[kt][3] += (float)sv[3];
      m0 = fmaxf(m0, acc[kt][0]); m1 = fmaxf(m1, acc[kt][1]);
      m2 = fmaxf(m2, acc[kt][2]); m3 = fmaxf(m3, acc[kt][3]);
    }
    float mB = fmaxf(fmaxf(m0, m1), fmaxf(m2, m3));
    mB = fmaxf(mB, __shfl_xor(mB, 16));
    mB = fmaxf(mB, __shfl_xor(mB, 32));

    const float m = fmaxf(mA, mB);
    const float scA = __builtin_amdgcn_exp2f(mA - m);

    s0 = 0.f; s1 = 0.f; s2 = 0.f; s3 = 0.f;
#pragma unroll
    for (int kt = 0; kt < 8; ++kt) {
      float p0 = __builtin_amdgcn_exp2f(acc[kt][0] - m);
      float p1 = __builtin_amdgcn_exp2f(acc[kt][1] - m);
      float p2 = __builtin_amdgcn_exp2f(acc[kt][2] - m);
      float p3 = __builtin_amdgcn_exp2f(acc[kt][3] - m);
      acc[kt][0] = p0; acc[kt][1] = p1; acc[kt][2] = p2; acc[kt][3] = p3;
      s0 += p0; s1 += p1; s2 += p2; s3 += p3;
    }
    float s = sA * scA + (s0 + s1) + (s2 + s3);
    s += __shfl_xor(s, 16);
    s += __shfl_xor(s, 32);
    const float rinv = 1.0f / s;

    // rescale phase-A PV then accumulate phase B
#pragma unroll
    for (int dt = 0; dt < 2; ++dt) {
      xa0[dt][0] *= scA; xa0[dt][1] *= scA; xa0[dt][2] *= scA; xa0[dt][3] *= scA;
      xa1[dt][0] *= scA; xa1[dt][1] *= scA; xa1[dt][2] *= scA; xa1[dt][3] *= scA;
    }
#pragma unroll
    for (int kt = 0; kt < 8; ++kt) {
      f16x2 p01 = pkrtz(acc[kt][0], acc[kt][1]);
      f16x2 p23 = pkrtz(acc[kt][2], acc[kt][3]);
      f16x4 pf = __builtin_shufflevector(p01, p23, 0, 1, 2, 3);
#pragma unroll
      for (int dt = 0; dt < 2; ++dt) {
        const int col = ((kt + 8) * 16 + g * 4) ^ ((r16 & 7) << 2);
        f16x4 vf = *((const f16x4*)&VT[dt * 16 + r16][col]);
        if (kt < 4)
          xa0[dt] = __builtin_amdgcn_mfma_f32_16x16x16f16(vf, pf, xa0[dt], 0, 0, 0);
        else
          xa1[dt] = __builtin_amdgcn_mfma_f32_16x16x16f16(vf, pf, xa1[dt], 0, 0, 0);
      }
    }

    // write x (f16) [b][token][192], normalized
    f16* xp = x16 + (size_t)(b * NTOK + qrow) * DIM + h * HD;
#pragma unroll
    for (int dt = 0; dt < 2; ++dt) {
      f16x2 o01 = pkrtz((xa0[dt][0] + xa1[dt][0]) * rinv,
                        (xa0[dt][1] + xa1[dt][1]) * rinv);
      f16x2 o23 = pkrtz((xa0[dt][2] + xa1[dt][2]) * rinv,
                        (xa0[dt][3] + xa1[dt][3]) * rinv);
      *((f16x4*)(xp + dt * 16 + g * 4)) = __builtin_shufflevector(o01, o23, 0, 1, 2, 3);
    }
  }
}

// ---------------------------------------------------------------------------
// Kernel 4: out = X16 @ W16^T + pb
// ---------------------------------------------------------------------------
__global__ __launch_bounds__(256) void proj_kernel(const f16* __restrict__ x16,
                                                   const f16* __restrict__ w16,
                                                   const float* __restrict__ pb,
                                                   float* __restrict__ out) {
  const int lane = threadIdx.x & 63;
  const int wave = threadIdx.x >> 6;
  const int g = lane >> 4;
  const int r16 = lane & 15;
  const int m0 = blockIdx.x * 64 + wave * 16;

  f32x4 acc[12];
#pragma unroll
  for (int jt = 0; jt < 12; ++jt) {
    acc[jt][0] = 0.f; acc[jt][1] = 0.f; acc[jt][2] = 0.f; acc[jt][3] = 0.f;
  }
#pragma unroll
  for (int cc = 0; cc < 6; ++cc) {
    f16x8 af = *((const f16x8*)(x16 + (size_t)(m0 + r16) * DIM + cc * 32 + g * 8));
#pragma unroll
    for (int jt = 0; jt < 12; ++jt) {
      f16x8 bf = *((const f16x8*)(w16 + (size_t)(jt * 16 + r16) * DIM + cc * 32 + g * 8));
      acc[jt] = __builtin_amdgcn_mfma_f32_16x16x32_f16(af, bf, acc[jt], 0, 0, 0);
    }
  }
#pragma unroll
  for (int jt = 0; jt < 12; ++jt) {
    int j = jt * 16 + r16;
    float bias = pb[j];
#pragma unroll
    for (int r = 0; r < 4; ++r) {
      out[(size_t)(m0 + g * 4 + r) * DIM + j] = acc[jt][r] + bias;
    }
  }
}

// ---------------------------------------------------------------------------
extern "C" void kernel_launch(void* const* d_in, const int* in_sizes, int n_in,
                              void* d_out, int out_size, void* d_ws, size_t ws_size,
                              hipStream_t stream) {
  const float* qkv  = (const float*)d_in[0];
  const int*   rpi  = (const int*)d_in[1];
  const float* mask = (const float*)d_in[2];
  const float* rpb  = (const float*)d_in[3];
  const float* pw   = (const float*)d_in[4];
  const float* pbv  = (const float*)d_in[5];
  float* out = (float*)d_out;

  char* ws = (char*)d_ws;
  f16* rpb16  = (f16*)ws;                            // 6*65536*2  =   786,432 B
  f16* mask16 = (f16*)(ws + 786432);                 // 16*65536*2 = 2,097,152 B
  f16* x16    = (f16*)(ws + 786432 + 2097152);       // 25,165,824 B
  f16* w16    = (f16*)(ws + 786432 + 2097152 + 25165824);  // 73,728 B

  prep_rpb_kernel<<<1536, 256, 0, stream>>>(rpi, rpb, rpb16);
  prep_mask_kernel<<<1024, 256, 0, stream>>>(mask, mask16);
  prep_w_kernel<<<144, 256, 0, stream>>>(pw, w16);
  attn_kernel<<<1536, 512, 0, stream>>>(qkv, rpb16, mask16, x16);
  proj_kernel<<<1024, 256, 0, stream>>>(x16, w16, pbv, out);
}

// Round 13
// 110.379 us; speedup vs baseline: 2.5437x; 1.4336x over previous
//
#include <hip/hip_runtime.h>
#include <hip/hip_bf16.h>

typedef _Float16 f16;
typedef _Float16 f16x2 __attribute__((ext_vector_type(2)));
typedef _Float16 f16x4 __attribute__((ext_vector_type(4)));
typedef _Float16 f16x8 __attribute__((ext_vector_type(8)));
typedef __fp16 h16x2 __attribute__((ext_vector_type(2)));
typedef float f32x4 __attribute__((ext_vector_type(4)));

// Problem constants
#define NHEADS 6
#define NTOK 256
#define NWINS 256
#define DIM 192
#define HD 32
#define C3 576
#define LOG2E 1.4426950408889634f
#define SCALE (0.17677669529663687f * LOG2E)

__device__ inline f16x2 pkrtz(float a, float b) {
  h16x2 r = __builtin_amdgcn_cvt_pkrtz(a, b);
  return __builtin_bit_cast(f16x2, r);
}

// ---------------------------------------------------------------------------
// Kernel 1: cb16 in FRAG-MAJOR f16 layout:
//   cb16[grp][q][ktp][g][e],  grp = mg*6+h, ktp in [0,8), g in [0,4), e in [0,8)
//   element (q, k) with k = (2*ktp + (e>>2))*16 + g*4 + (e&3)
// One f16x8 load per lane covers a kt-PAIR slice (16 B, 64 B segments).
// 12.6 MB total; per-grp slice 128 KB -> L2-resident with XCD pinning.
// ---------------------------------------------------------------------------
__global__ __launch_bounds__(256) void prep_cb_kernel(const int* __restrict__ rpi,
                                                      const float* __restrict__ mask,
                                                      const float* __restrict__ rpb,
                                                      f16* __restrict__ cb) {
  int idx = blockIdx.x * 256 + threadIdx.x;
  int rem = idx & 255;
  int q = (idx >> 8) & 255;
  int t = idx >> 16;           // t = mg*6 + h
  int h = t % 6;
  int mg = t / 6;
  int ktp = rem >> 5;
  int gg = (rem >> 3) & 3;
  int e = rem & 7;
  int k = (2 * ktp + (e >> 2)) * 16 + gg * 4 + (e & 3);
  float v = (rpb[rpi[(q << 8) | k] * 6 + h] + mask[(mg << 16) | (q << 8) | k]) * LOG2E;
  cb[idx] = (f16)v;
}

// ---------------------------------------------------------------------------
// Kernel 2: W (192x192) fp32 -> f16
// ---------------------------------------------------------------------------
__global__ __launch_bounds__(256) void prep_w_kernel(const float* __restrict__ w,
                                                     f16* __restrict__ w16) {
  int i = blockIdx.x * 256 + threadIdx.x;
  if (i < DIM * DIM) w16[i] = (f16)w[i];
}

__device__ inline f16x8 q_to_f16(float4 a, float4 b) {
  f16x2 p0 = pkrtz(a.x * SCALE, a.y * SCALE);
  f16x2 p1 = pkrtz(a.z * SCALE, a.w * SCALE);
  f16x2 p2 = pkrtz(b.x * SCALE, b.y * SCALE);
  f16x2 p3 = pkrtz(b.z * SCALE, b.w * SCALE);
  f16x4 lo = __builtin_shufflevector(p0, p1, 0, 1, 2, 3);
  f16x4 hi = __builtin_shufflevector(p2, p3, 0, 1, 2, 3);
  return __builtin_shufflevector(lo, hi, 0, 1, 2, 3, 4, 5, 6, 7);
}

// ---------------------------------------------------------------------------
// Kernel 3: fused window attention. Block = (b, h). 512 thr = 8 waves.
// r13 vs r10:
//  - cb is f16 frag-major (HALF the dominant L3 stream: 400 -> 200 MB logical)
//  - blockIdx pinning: idx = grp + 96*j, grp = (b&15)*6+h. 96 % 8 == 0 so all
//    16 blocks sharing a 128 KB cb slice land on one XCD -> slice L2-resident
//    (12 slices * 128 KB = 1.5 MB per XCD L2). r11 traffic audit: cb was 74%
//    of a ~540 MB logical stream at the ~10 TB/s L3 ceiling = the 97 us.
//  - acc seeded by 4 cvts/kt from the f16 (NO VALU adds — r12's mistake).
// Otherwise r10 structure: (512,4), online softmax 2 k-halves, PV dual chains.
// ---------------------------------------------------------------------------
__global__ __launch_bounds__(512, 4) void attn_kernel(const float* __restrict__ qkv,
                                                      const f16* __restrict__ cb,
                                                      f16* __restrict__ x16) {
  const int idx = blockIdx.x;
  const int grp = idx % 96;            // (b&15)*6 + h  — pinned to XCD grp%8
  const int jhi = idx / 96;            // b >> 4
  const int b = (jhi << 4) | (grp / 6);
  const int h = grp % 6;
  const int tid = threadIdx.x;
  const int lane = tid & 63;
  const int wave = tid >> 6;
  const int g = lane >> 4;
  const int r16 = lane & 15;

  __shared__ f16 Klin[16 * 64 * 8];
  __shared__ f16 VT[32][264];

  // ---- stage K (waves 0-3) / V (waves 4-7) ----
  {
    const int t = tid & 255;
    const int srow = t >> 3;
    const int part = t & 7;
    const bool isK = tid < 256;
    const float* base = qkv + (size_t)(b * NTOK + srow) * C3 + DIM + (isK ? 0 : DIM)
                        + h * HD + part * 4;
    const int gg = part >> 1;
    const int half = part & 1;
    const int d0 = part * 4;
#pragma unroll
    for (int batch = 0; batch < 2; ++batch) {
      float4 v4[4];
#pragma unroll
      for (int rg = 0; rg < 4; ++rg)
        v4[rg] = *(const float4*)(base + (size_t)((batch * 4 + rg) * 32) * C3);
#pragma unroll
      for (int rg = 0; rg < 4; ++rg) {
        const int row = (batch * 4 + rg) * 32 + srow;
        if (isK) {
          const int slot = ((row >> 4) * 64) + gg * 16 + ((row & 15) ^ (gg << 2));
          f16x2 k01 = pkrtz(v4[rg].x, v4[rg].y);
          f16x2 k23 = pkrtz(v4[rg].z, v4[rg].w);
          *((f16x4*)&Klin[slot * 8 + half * 4]) =
              __builtin_shufflevector(k01, k23, 0, 1, 2, 3);
        } else {
          VT[d0 + 0][row ^ (((d0 + 0) & 7) << 2)] = (f16)v4[rg].x;
          VT[d0 + 1][row ^ (((d0 + 1) & 7) << 2)] = (f16)v4[rg].y;
          VT[d0 + 2][row ^ (((d0 + 2) & 7) << 2)] = (f16)v4[rg].z;
          VT[d0 + 3][row ^ (((d0 + 3) & 7) << 2)] = (f16)v4[rg].w;
        }
      }
    }
  }
  __syncthreads();

  const int qbase = wave * 32;
  const f16* cbb = cb + ((size_t)grp << 16);
  const int krd = (lane & 48) + ((lane & 15) ^ ((lane >> 2) & 12));

#pragma unroll
  for (int c = 0; c < 2; ++c) {
    const int qrow = qbase + c * 16 + r16;
    const float* qp = qkv + (size_t)(b * NTOK + qrow) * C3 + h * HD + g * 8;
    f16x8 qf = q_to_f16(((const float4*)qp)[0], ((const float4*)qp)[1]);
    const f16* cbq = cbb + (qrow << 8) + g * 8;   // frag-major row base

    // ================= phase A: keys 0..127 =================
    // one f16x8 per kt-PAIR (4 loads, 64B segments, L2-resident slice)
    f16x8 cv[4];
#pragma unroll
    for (int kp = 0; kp < 4; ++kp) cv[kp] = *((const f16x8*)(cbq + kp * 32));
    f32x4 acc[8];
#pragma unroll
    for (int kp = 0; kp < 4; ++kp) {
#pragma unroll
      for (int r = 0; r < 4; ++r) {
        acc[2 * kp][r] = (float)cv[kp][r];
        acc[2 * kp + 1][r] = (float)cv[kp][4 + r];
      }
    }
#pragma unroll
    for (int kt = 0; kt < 8; ++kt) {
      f16x8 af = *((const f16x8*)&Klin[(kt * 64 + krd) * 8]);
      acc[kt] = __builtin_amdgcn_mfma_f32_16x16x32_f16(af, qf, acc[kt], 0, 0, 0);
    }

    float m0 = fmaxf(fmaxf(acc[0][0], acc[1][0]), fmaxf(acc[2][0], acc[3][0]));
    float m1 = fmaxf(fmaxf(acc[0][1], acc[1][1]), fmaxf(acc[2][1], acc[3][1]));
    float m2 = fmaxf(fmaxf(acc[0][2], acc[1][2]), fmaxf(acc[2][2], acc[3][2]));
    float m3 = fmaxf(fmaxf(acc[0][3], acc[1][3]), fmaxf(acc[2][3], acc[3][3]));
#pragma unroll
    for (int kt = 4; kt < 8; ++kt) {
      m0 = fmaxf(m0, acc[kt][0]); m1 = fmaxf(m1, acc[kt][1]);
      m2 = fmaxf(m2, acc[kt][2]); m3 = fmaxf(m3, acc[kt][3]);
    }
    float mA = fmaxf(fmaxf(m0, m1), fmaxf(m2, m3));
    mA = fmaxf(mA, __shfl_xor(mA, 16));
    mA = fmaxf(mA, __shfl_xor(mA, 32));

    float s0 = 0.f, s1 = 0.f, s2 = 0.f, s3 = 0.f;
#pragma unroll
    for (int kt = 0; kt < 8; ++kt) {
      float p0 = __builtin_amdgcn_exp2f(acc[kt][0] - mA);
      float p1 = __builtin_amdgcn_exp2f(acc[kt][1] - mA);
      float p2 = __builtin_amdgcn_exp2f(acc[kt][2] - mA);
      float p3 = __builtin_amdgcn_exp2f(acc[kt][3] - mA);
      acc[kt][0] = p0; acc[kt][1] = p1; acc[kt][2] = p2; acc[kt][3] = p3;
      s0 += p0; s1 += p1; s2 += p2; s3 += p3;
    }
    float sA = (s0 + s1) + (s2 + s3);

    // PV phase A — 2 chains per dt
    f32x4 xa0[2], xa1[2];
#pragma unroll
    for (int dt = 0; dt < 2; ++dt) {
      xa0[dt][0] = 0.f; xa0[dt][1] = 0.f; xa0[dt][2] = 0.f; xa0[dt][3] = 0.f;
      xa1[dt][0] = 0.f; xa1[dt][1] = 0.f; xa1[dt][2] = 0.f; xa1[dt][3] = 0.f;
    }
#pragma unroll
    for (int kt = 0; kt < 8; ++kt) {
      f16x2 p01 = pkrtz(acc[kt][0], acc[kt][1]);
      f16x2 p23 = pkrtz(acc[kt][2], acc[kt][3]);
      f16x4 pf = __builtin_shufflevector(p01, p23, 0, 1, 2, 3);
#pragma unroll
      for (int dt = 0; dt < 2; ++dt) {
        const int col = (kt * 16 + g * 4) ^ ((r16 & 7) << 2);
        f16x4 vf = *((const f16x4*)&VT[dt * 16 + r16][col]);
        if (kt < 4)
          xa0[dt] = __builtin_amdgcn_mfma_f32_16x16x16f16(vf, pf, xa0[dt], 0, 0, 0);
        else
          xa1[dt] = __builtin_amdgcn_mfma_f32_16x16x16f16(vf, pf, xa1[dt], 0, 0, 0);
      }
    }

    // ================= phase B: keys 128..255 =================
#pragma unroll
    for (int kp = 0; kp < 4; ++kp) cv[kp] = *((const f16x8*)(cbq + 128 + kp * 32));
#pragma unroll
    for (int kp = 0; kp < 4; ++kp) {
#pragma unroll
      for (int r = 0; r < 4; ++r) {
        acc[2 * kp][r] = (float)cv[kp][r];
        acc[2 * kp + 1][r] = (float)cv[kp][4 + r];
      }
    }
#pragma unroll
    for (int kt = 0; kt < 8; ++kt) {
      f16x8 af = *((const f16x8*)&Klin[((kt + 8) * 64 + krd) * 8]);
      acc[kt] = __builtin_amdgcn_mfma_f32_16x16x32_f16(af, qf, acc[kt], 0, 0, 0);
    }

    m0 = fmaxf(fmaxf(acc[0][0], acc[1][0]), fmaxf(acc[2][0], acc[3][0]));
    m1 = fmaxf(fmaxf(acc[0][1], acc[1][1]), fmaxf(acc[2][1], acc[3][1]));
    m2 = fmaxf(fmaxf(acc[0][2], acc[1][2]), fmaxf(acc[2][2], acc[3][2]));
    m3 = fmaxf(fmaxf(acc[0][3], acc[1][3]), fmaxf(acc[2][3], acc[3][3]));
#pragma unroll
    for (int kt = 4; kt < 8; ++kt) {
      m0 = fmaxf(m0, acc[kt][0]); m1 = fmaxf(m1, acc[kt][1]);
      m2 = fmaxf(m2, acc[kt][2]); m3 = fmaxf(m3, acc[kt][3]);
    }
    float mB = fmaxf(fmaxf(m0, m1), fmaxf(m2, m3));
    mB = fmaxf(mB, __shfl_xor(mB, 16));
    mB = fmaxf(mB, __shfl_xor(mB, 32));

    const float m = fmaxf(mA, mB);
    const float scA = __builtin_amdgcn_exp2f(mA - m);

    s0 = 0.f; s1 = 0.f; s2 = 0.f; s3 = 0.f;
#pragma unroll
    for (int kt = 0; kt < 8; ++kt) {
      float p0 = __builtin_amdgcn_exp2f(acc[kt][0] - m);
      float p1 = __builtin_amdgcn_exp2f(acc[kt][1] - m);
      float p2 = __builtin_amdgcn_exp2f(acc[kt][2] - m);
      float p3 = __builtin_amdgcn_exp2f(acc[kt][3] - m);
      acc[kt][0] = p0; acc[kt][1] = p1; acc[kt][2] = p2; acc[kt][3] = p3;
      s0 += p0; s1 += p1; s2 += p2; s3 += p3;
    }
    float s = sA * scA + (s0 + s1) + (s2 + s3);
    s += __shfl_xor(s, 16);
    s += __shfl_xor(s, 32);
    const float rinv = 1.0f / s;

    // rescale phase-A PV then accumulate phase B
#pragma unroll
    for (int dt = 0; dt < 2; ++dt) {
      xa0[dt][0] *= scA; xa0[dt][1] *= scA; xa0[dt][2] *= scA; xa0[dt][3] *= scA;
      xa1[dt][0] *= scA; xa1[dt][1] *= scA; xa1[dt][2] *= scA; xa1[dt][3] *= scA;
    }
#pragma unroll
    for (int kt = 0; kt < 8; ++kt) {
      f16x2 p01 = pkrtz(acc[kt][0], acc[kt][1]);
      f16x2 p23 = pkrtz(acc[kt][2], acc[kt][3]);
      f16x4 pf = __builtin_shufflevector(p01, p23, 0, 1, 2, 3);
#pragma unroll
      for (int dt = 0; dt < 2; ++dt) {
        const int col = ((kt + 8) * 16 + g * 4) ^ ((r16 & 7) << 2);
        f16x4 vf = *((const f16x4*)&VT[dt * 16 + r16][col]);
        if (kt < 4)
          xa0[dt] = __builtin_amdgcn_mfma_f32_16x16x16f16(vf, pf, xa0[dt], 0, 0, 0);
        else
          xa1[dt] = __builtin_amdgcn_mfma_f32_16x16x16f16(vf, pf, xa1[dt], 0, 0, 0);
      }
    }

    // write x (f16) [b][token][192], normalized
    f16* xp = x16 + (size_t)(b * NTOK + qrow) * DIM + h * HD;
#pragma unroll
    for (int dt = 0; dt < 2; ++dt) {
      f16x2 o01 = pkrtz((xa0[dt][0] + xa1[dt][0]) * rinv,
                        (xa0[dt][1] + xa1[dt][1]) * rinv);
      f16x2 o23 = pkrtz((xa0[dt][2] + xa1[dt][2]) * rinv,
                        (xa0[dt][3] + xa1[dt][3]) * rinv);
      *((f16x4*)(xp + dt * 16 + g * 4)) = __builtin_shufflevector(o01, o23, 0, 1, 2, 3);
    }
  }
}

// ---------------------------------------------------------------------------
// Kernel 4: out = X16 @ W16^T + pb
// ---------------------------------------------------------------------------
__global__ __launch_bounds__(256) void proj_kernel(const f16* __restrict__ x16,
                                                   const f16* __restrict__ w16,
                                                   const float* __restrict__ pb,
                                                   float* __restrict__ out) {
  const int lane = threadIdx.x & 63;
  const int wave = threadIdx.x >> 6;
  const int g = lane >> 4;
  const int r16 = lane & 15;
  const int m0 = blockIdx.x * 64 + wave * 16;

  f32x4 acc[12];
#pragma unroll
  for (int jt = 0; jt < 12; ++jt) {
    acc[jt][0] = 0.f; acc[jt][1] = 0.f; acc[jt][2] = 0.f; acc[jt][3] = 0.f;
  }
#pragma unroll
  for (int cc = 0; cc < 6; ++cc) {
    f16x8 af = *((const f16x8*)(x16 + (size_t)(m0 + r16) * DIM + cc * 32 + g * 8));
#pragma unroll
    for (int jt = 0; jt < 12; ++jt) {
      f16x8 bf = *((const f16x8*)(w16 + (size_t)(jt * 16 + r16) * DIM + cc * 32 + g * 8));
      acc[jt] = __builtin_amdgcn_mfma_f32_16x16x32_f16(af, bf, acc[jt], 0, 0, 0);
    }
  }
#pragma unroll
  for (int jt = 0; jt < 12; ++jt) {
    int j = jt * 16 + r16;
    float bias = pb[j];
#pragma unroll
    for (int r = 0; r < 4; ++r) {
      out[(size_t)(m0 + g * 4 + r) * DIM + j] = acc[jt][r] + bias;
    }
  }
}

// ---------------------------------------------------------------------------
extern "C" void kernel_launch(void* const* d_in, const int* in_sizes, int n_in,
                              void* d_out, int out_size, void* d_ws, size_t ws_size,
                              hipStream_t stream) {
  const float* qkv  = (const float*)d_in[0];
  const int*   rpi  = (const int*)d_in[1];
  const float* mask = (const float*)d_in[2];
  const float* rpb  = (const float*)d_in[3];
  const float* pw   = (const float*)d_in[4];
  const float* pbv  = (const float*)d_in[5];
  float* out = (float*)d_out;

  char* ws = (char*)d_ws;
  f16* cb16 = (f16*)ws;                              // 16*6*65536*2 = 12,582,912 B
  f16* x16  = (f16*)(ws + 12582912);                 // 25,165,824 B
  f16* w16  = (f16*)(ws + 12582912 + 25165824);      // 73,728 B

  prep_cb_kernel<<<24576, 256, 0, stream>>>(rpi, mask, rpb, cb16);
  prep_w_kernel<<<144, 256, 0, stream>>>(pw, w16);
  attn_kernel<<<1536, 512, 0, stream>>>(qkv, cb16, x16);
  proj_kernel<<<1024, 256, 0, stream>>>(x16, w16, pbv, out);
}

// Round 14
// 108.943 us; speedup vs baseline: 2.5772x; 1.0132x over previous
//
#include <hip/hip_runtime.h>
#include <hip/hip_bf16.h>

typedef _Float16 f16;
typedef _Float16 f16x2 __attribute__((ext_vector_type(2)));
typedef _Float16 f16x4 __attribute__((ext_vector_type(4)));
typedef _Float16 f16x8 __attribute__((ext_vector_type(8)));
typedef __fp16 h16x2 __attribute__((ext_vector_type(2)));
typedef float f32x4 __attribute__((ext_vector_type(4)));

// Problem constants
#define NHEADS 6
#define NTOK 256
#define NWINS 256
#define DIM 192
#define HD 32
#define C3 576
#define LOG2E 1.4426950408889634f
#define SCALE (0.17677669529663687f * LOG2E)

__device__ inline f16x2 pkrtz(float a, float b) {
  h16x2 r = __builtin_amdgcn_cvt_pkrtz(a, b);
  return __builtin_bit_cast(f16x2, r);
}

// ---------------------------------------------------------------------------
// Kernel 1: cb16 in FRAG-MAJOR f16 layout (r13):
//   cb16[grp][q][ktp][g][e], grp = mg*6+h; element (q,k),
//   k = (2*ktp + (e>>2))*16 + g*4 + (e&3)
// ---------------------------------------------------------------------------
__global__ __launch_bounds__(256) void prep_cb_kernel(const int* __restrict__ rpi,
                                                      const float* __restrict__ mask,
                                                      const float* __restrict__ rpb,
                                                      f16* __restrict__ cb) {
  int idx = blockIdx.x * 256 + threadIdx.x;
  int rem = idx & 255;
  int q = (idx >> 8) & 255;
  int t = idx >> 16;           // t = mg*6 + h
  int h = t % 6;
  int mg = t / 6;
  int ktp = rem >> 5;
  int gg = (rem >> 3) & 3;
  int e = rem & 7;
  int k = (2 * ktp + (e >> 2)) * 16 + gg * 4 + (e & 3);
  float v = (rpb[rpi[(q << 8) | k] * 6 + h] + mask[(mg << 16) | (q << 8) | k]) * LOG2E;
  cb[idx] = (f16)v;
}

// ---------------------------------------------------------------------------
// Kernel 2: W (192x192) fp32 -> f16
// ---------------------------------------------------------------------------
__global__ __launch_bounds__(256) void prep_w_kernel(const float* __restrict__ w,
                                                     f16* __restrict__ w16) {
  int i = blockIdx.x * 256 + threadIdx.x;
  if (i < DIM * DIM) w16[i] = (f16)w[i];
}

__device__ inline f16x8 q_to_f16(float4 a, float4 b) {
  f16x2 p0 = pkrtz(a.x * SCALE, a.y * SCALE);
  f16x2 p1 = pkrtz(a.z * SCALE, a.w * SCALE);
  f16x2 p2 = pkrtz(b.x * SCALE, b.y * SCALE);
  f16x2 p3 = pkrtz(b.z * SCALE, b.w * SCALE);
  f16x4 lo = __builtin_shufflevector(p0, p1, 0, 1, 2, 3);
  f16x4 hi = __builtin_shufflevector(p2, p3, 0, 1, 2, 3);
  return __builtin_shufflevector(lo, hi, 0, 1, 2, 3, 4, 5, 6, 7);
}

// ---------------------------------------------------------------------------
// Kernel 3: fused window attention — r14 persistent double-buffered pairs.
// Grid 768; block idx -> grp = idx%96 (cb slice + XCD pin), pr = idx/96.
// Block processes pairs b = {(2pr)<<4 | blo, (2pr+1)<<4 | blo} (same grp).
// While computing pair0 from LDS buf0, pair1's K/V loads are issued at
// chunk starts and converted/written to buf1 after the QK MFMAs
// (issue-early/write-late): pair1 staging latency hides under compute.
// One __syncthreads per pair boundary. Else r13: f16 frag-major cb seeds
// MFMA C, (512,4), online softmax 2 k-halves, PV dual chains.
// ---------------------------------------------------------------------------
__global__ __launch_bounds__(512, 4) void attn_kernel(const float* __restrict__ qkv,
                                                      const f16* __restrict__ cb,
                                                      f16* __restrict__ x16) {
  const int idx = blockIdx.x;
  const int grp = idx % 96;            // (b&15)*6 + h — pinned to XCD grp%8
  const int pr = idx / 96;             // 0..7
  const int h = grp % 6;
  const int blo = grp / 6;             // b & 15
  const int tid = threadIdx.x;
  const int lane = tid & 63;
  const int wave = tid >> 6;
  const int g = lane >> 4;
  const int r16 = lane & 15;

  __shared__ f16 Klin[2][16 * 64 * 8];
  __shared__ f16 VT[2][32][264];

  // staging role
  const int t = tid & 255;
  const int srow = t >> 3;
  const int part = t & 7;
  const bool isK = tid < 256;
  const int gg = part >> 1;
  const int half = part & 1;
  const int d0 = part * 4;

  const int b0 = ((pr * 2) << 4) | blo;
  const int b1 = ((pr * 2 + 1) << 4) | blo;
  const float* sbase0 = qkv + (size_t)(b0 * NTOK + srow) * C3 + DIM + (isK ? 0 : DIM)
                        + h * HD + part * 4;
  const float* sbase1 = qkv + (size_t)(b1 * NTOK + srow) * C3 + DIM + (isK ? 0 : DIM)
                        + h * HD + part * 4;

  // convert + LDS-write 4 row-groups into buffer `buf`
  auto stage_write = [&](int buf, int rgbase, const float4* v4) {
#pragma unroll
    for (int rg = 0; rg < 4; ++rg) {
      const int row = (rgbase + rg) * 32 + srow;
      if (isK) {
        const int slot = ((row >> 4) * 64) + gg * 16 + ((row & 15) ^ (gg << 2));
        f16x2 k01 = pkrtz(v4[rg].x, v4[rg].y);
        f16x2 k23 = pkrtz(v4[rg].z, v4[rg].w);
        *((f16x4*)&Klin[buf][slot * 8 + half * 4]) =
            __builtin_shufflevector(k01, k23, 0, 1, 2, 3);
      } else {
        VT[buf][d0 + 0][row ^ (((d0 + 0) & 7) << 2)] = (f16)v4[rg].x;
        VT[buf][d0 + 1][row ^ (((d0 + 1) & 7) << 2)] = (f16)v4[rg].y;
        VT[buf][d0 + 2][row ^ (((d0 + 2) & 7) << 2)] = (f16)v4[rg].z;
        VT[buf][d0 + 3][row ^ (((d0 + 3) & 7) << 2)] = (f16)v4[rg].w;
      }
    }
  };

  // ---- pair 0: full stage into buffer 0 ----
  {
    float4 s4[8];
#pragma unroll
    for (int i = 0; i < 8; ++i)
      s4[i] = *(const float4*)(sbase0 + (size_t)(i * 32) * C3);
    stage_write(0, 0, s4);
    stage_write(0, 4, s4 + 4);
  }
  __syncthreads();

  const f16* cbb = cb + ((size_t)grp << 16);
  const int krd = (lane & 48) + ((lane & 15) ^ ((lane >> 2) & 12));
  const int qbase = wave * 32;

#pragma unroll
  for (int pair = 0; pair < 2; ++pair) {
    const int b = (pair == 0) ? b0 : b1;

#pragma unroll
    for (int c = 0; c < 2; ++c) {
      // issue next pair's staging loads (batch c: rows c*128..c*128+127)
      float4 n4[4];
      if (pair == 0) {
#pragma unroll
        for (int i = 0; i < 4; ++i)
          n4[i] = *(const float4*)(sbase1 + (size_t)((c * 4 + i) * 32) * C3);
      }

      const int qrow = qbase + c * 16 + r16;
      const float* qp = qkv + (size_t)(b * NTOK + qrow) * C3 + h * HD + g * 8;
      f16x8 qf = q_to_f16(((const float4*)qp)[0], ((const float4*)qp)[1]);
      const f16* cbq = cbb + (qrow << 8) + g * 8;

      // ================= phase A: keys 0..127 =================
      f16x8 cv[4];
#pragma unroll
      for (int kp = 0; kp < 4; ++kp) cv[kp] = *((const f16x8*)(cbq + kp * 32));
      f32x4 acc[8];
#pragma unroll
      for (int kp = 0; kp < 4; ++kp) {
#pragma unroll
        for (int r = 0; r < 4; ++r) {
          acc[2 * kp][r] = (float)cv[kp][r];
          acc[2 * kp + 1][r] = (float)cv[kp][4 + r];
        }
      }
#pragma unroll
      for (int kt = 0; kt < 8; ++kt) {
        f16x8 af = *((const f16x8*)&Klin[pair][(kt * 64 + krd) * 8]);
        acc[kt] = __builtin_amdgcn_mfma_f32_16x16x32_f16(af, qf, acc[kt], 0, 0, 0);
      }

      // write next pair's staging batch (loads have had QK latency to land)
      if (pair == 0) stage_write(1, c * 4, n4);

      float m0 = fmaxf(fmaxf(acc[0][0], acc[1][0]), fmaxf(acc[2][0], acc[3][0]));
      float m1 = fmaxf(fmaxf(acc[0][1], acc[1][1]), fmaxf(acc[2][1], acc[3][1]));
      float m2 = fmaxf(fmaxf(acc[0][2], acc[1][2]), fmaxf(acc[2][2], acc[3][2]));
      float m3 = fmaxf(fmaxf(acc[0][3], acc[1][3]), fmaxf(acc[2][3], acc[3][3]));
#pragma unroll
      for (int kt = 4; kt < 8; ++kt) {
        m0 = fmaxf(m0, acc[kt][0]); m1 = fmaxf(m1, acc[kt][1]);
        m2 = fmaxf(m2, acc[kt][2]); m3 = fmaxf(m3, acc[kt][3]);
      }
      float mA = fmaxf(fmaxf(m0, m1), fmaxf(m2, m3));
      mA = fmaxf(mA, __shfl_xor(mA, 16));
      mA = fmaxf(mA, __shfl_xor(mA, 32));

      float s0 = 0.f, s1 = 0.f, s2 = 0.f, s3 = 0.f;
#pragma unroll
      for (int kt = 0; kt < 8; ++kt) {
        float p0 = __builtin_amdgcn_exp2f(acc[kt][0] - mA);
        float p1 = __builtin_amdgcn_exp2f(acc[kt][1] - mA);
        float p2 = __builtin_amdgcn_exp2f(acc[kt][2] - mA);
        float p3 = __builtin_amdgcn_exp2f(acc[kt][3] - mA);
        acc[kt][0] = p0; acc[kt][1] = p1; acc[kt][2] = p2; acc[kt][3] = p3;
        s0 += p0; s1 += p1; s2 += p2; s3 += p3;
      }
      float sA = (s0 + s1) + (s2 + s3);

      // PV phase A — 2 chains per dt
      f32x4 xa0[2], xa1[2];
#pragma unroll
      for (int dt = 0; dt < 2; ++dt) {
        xa0[dt][0] = 0.f; xa0[dt][1] = 0.f; xa0[dt][2] = 0.f; xa0[dt][3] = 0.f;
        xa1[dt][0] = 0.f; xa1[dt][1] = 0.f; xa1[dt][2] = 0.f; xa1[dt][3] = 0.f;
      }
#pragma unroll
      for (int kt = 0; kt < 8; ++kt) {
        f16x2 p01 = pkrtz(acc[kt][0], acc[kt][1]);
        f16x2 p23 = pkrtz(acc[kt][2], acc[kt][3]);
        f16x4 pf = __builtin_shufflevector(p01, p23, 0, 1, 2, 3);
#pragma unroll
        for (int dt = 0; dt < 2; ++dt) {
          const int col = (kt * 16 + g * 4) ^ ((r16 & 7) << 2);
          f16x4 vf = *((const f16x4*)&VT[pair][dt * 16 + r16][col]);
          if (kt < 4)
            xa0[dt] = __builtin_amdgcn_mfma_f32_16x16x16f16(vf, pf, xa0[dt], 0, 0, 0);
          else
            xa1[dt] = __builtin_amdgcn_mfma_f32_16x16x16f16(vf, pf, xa1[dt], 0, 0, 0);
        }
      }

      // ================= phase B: keys 128..255 =================
#pragma unroll
      for (int kp = 0; kp < 4; ++kp) cv[kp] = *((const f16x8*)(cbq + 128 + kp * 32));
#pragma unroll
      for (int kp = 0; kp < 4; ++kp) {
#pragma unroll
        for (int r = 0; r < 4; ++r) {
          acc[2 * kp][r] = (float)cv[kp][r];
          acc[2 * kp + 1][r] = (float)cv[kp][4 + r];
        }
      }
#pragma unroll
      for (int kt = 0; kt < 8; ++kt) {
        f16x8 af = *((const f16x8*)&Klin[pair][((kt + 8) * 64 + krd) * 8]);
        acc[kt] = __builtin_amdgcn_mfma_f32_16x16x32_f16(af, qf, acc[kt], 0, 0, 0);
      }

      m0 = fmaxf(fmaxf(acc[0][0], acc[1][0]), fmaxf(acc[2][0], acc[3][0]));
      m1 = fmaxf(fmaxf(acc[0][1], acc[1][1]), fmaxf(acc[2][1], acc[3][1]));
      m2 = fmaxf(fmaxf(acc[0][2], acc[1][2]), fmaxf(acc[2][2], acc[3][2]));
      m3 = fmaxf(fmaxf(acc[0][3], acc[1][3]), fmaxf(acc[2][3], acc[3][3]));
#pragma unroll
      for (int kt = 4; kt < 8; ++kt) {
        m0 = fmaxf(m0, acc[kt][0]); m1 = fmaxf(m1, acc[kt][1]);
        m2 = fmaxf(m2, acc[kt][2]); m3 = fmaxf(m3, acc[kt][3]);
      }
      float mB = fmaxf(fmaxf(m0, m1), fmaxf(m2, m3));
      mB = fmaxf(mB, __shfl_xor(mB, 16));
      mB = fmaxf(mB, __shfl_xor(mB, 32));

      const float m = fmaxf(mA, mB);
      const float scA = __builtin_amdgcn_exp2f(mA - m);

      s0 = 0.f; s1 = 0.f; s2 = 0.f; s3 = 0.f;
#pragma unroll
      for (int kt = 0; kt < 8; ++kt) {
        float p0 = __builtin_amdgcn_exp2f(acc[kt][0] - m);
        float p1 = __builtin_amdgcn_exp2f(acc[kt][1] - m);
        float p2 = __builtin_amdgcn_exp2f(acc[kt][2] - m);
        float p3 = __builtin_amdgcn_exp2f(acc[kt][3] - m);
        acc[kt][0] = p0; acc[kt][1] = p1; acc[kt][2] = p2; acc[kt][3] = p3;
        s0 += p0; s1 += p1; s2 += p2; s3 += p3;
      }
      float s = sA * scA + (s0 + s1) + (s2 + s3);
      s += __shfl_xor(s, 16);
      s += __shfl_xor(s, 32);
      const float rinv = 1.0f / s;

#pragma unroll
      for (int dt = 0; dt < 2; ++dt) {
        xa0[dt][0] *= scA; xa0[dt][1] *= scA; xa0[dt][2] *= scA; xa0[dt][3] *= scA;
        xa1[dt][0] *= scA; xa1[dt][1] *= scA; xa1[dt][2] *= scA; xa1[dt][3] *= scA;
      }
#pragma unroll
      for (int kt = 0; kt < 8; ++kt) {
        f16x2 p01 = pkrtz(acc[kt][0], acc[kt][1]);
        f16x2 p23 = pkrtz(acc[kt][2], acc[kt][3]);
        f16x4 pf = __builtin_shufflevector(p01, p23, 0, 1, 2, 3);
#pragma unroll
        for (int dt = 0; dt < 2; ++dt) {
          const int col = ((kt + 8) * 16 + g * 4) ^ ((r16 & 7) << 2);
          f16x4 vf = *((const f16x4*)&VT[pair][dt * 16 + r16][col]);
          if (kt < 4)
            xa0[dt] = __builtin_amdgcn_mfma_f32_16x16x16f16(vf, pf, xa0[dt], 0, 0, 0);
          else
            xa1[dt] = __builtin_amdgcn_mfma_f32_16x16x16f16(vf, pf, xa1[dt], 0, 0, 0);
        }
      }

      // write x (f16) [b][token][192], normalized
      f16* xp = x16 + (size_t)(b * NTOK + qrow) * DIM + h * HD;
#pragma unroll
      for (int dt = 0; dt < 2; ++dt) {
        f16x2 o01 = pkrtz((xa0[dt][0] + xa1[dt][0]) * rinv,
                          (xa0[dt][1] + xa1[dt][1]) * rinv);
        f16x2 o23 = pkrtz((xa0[dt][2] + xa1[dt][2]) * rinv,
                          (xa0[dt][3] + xa1[dt][3]) * rinv);
        *((f16x4*)(xp + dt * 16 + g * 4)) = __builtin_shufflevector(o01, o23, 0, 1, 2, 3);
      }
    }

    // pair boundary: buf1 staging writes must be visible before pair1 reads
    if (pair == 0) __syncthreads();
  }
}

// ---------------------------------------------------------------------------
// Kernel 4: out = X16 @ W16^T + pb
// ---------------------------------------------------------------------------
__global__ __launch_bounds__(256) void proj_kernel(const f16* __restrict__ x16,
                                                   const f16* __restrict__ w16,
                                                   const float* __restrict__ pb,
                                                   float* __restrict__ out) {
  const int lane = threadIdx.x & 63;
  const int wave = threadIdx.x >> 6;
  const int g = lane >> 4;
  const int r16 = lane & 15;
  const int m0 = blockIdx.x * 64 + wave * 16;

  f32x4 acc[12];
#pragma unroll
  for (int jt = 0; jt < 12; ++jt) {
    acc[jt][0] = 0.f; acc[jt][1] = 0.f; acc[jt][2] = 0.f; acc[jt][3] = 0.f;
  }
#pragma unroll
  for (int cc = 0; cc < 6; ++cc) {
    f16x8 af = *((const f16x8*)(x16 + (size_t)(m0 + r16) * DIM + cc * 32 + g * 8));
#pragma unroll
    for (int jt = 0; jt < 12; ++jt) {
      f16x8 bf = *((const f16x8*)(w16 + (size_t)(jt * 16 + r16) * DIM + cc * 32 + g * 8));
      acc[jt] = __builtin_amdgcn_mfma_f32_16x16x32_f16(af, bf, acc[jt], 0, 0, 0);
    }
  }
#pragma unroll
  for (int jt = 0; jt < 12; ++jt) {
    int j = jt * 16 + r16;
    float bias = pb[j];
#pragma unroll
    for (int r = 0; r < 4; ++r) {
      out[(size_t)(m0 + g * 4 + r) * DIM + j] = acc[jt][r] + bias;
    }
  }
}

// ---------------------------------------------------------------------------
extern "C" void kernel_launch(void* const* d_in, const int* in_sizes, int n_in,
                              void* d_out, int out_size, void* d_ws, size_t ws_size,
                              hipStream_t stream) {
  const float* qkv  = (const float*)d_in[0];
  const int*   rpi  = (const int*)d_in[1];
  const float* mask = (const float*)d_in[2];
  const float* rpb  = (const float*)d_in[3];
  const float* pw   = (const float*)d_in[4];
  const float* pbv  = (const float*)d_in[5];
  float* out = (float*)d_out;

  char* ws = (char*)d_ws;
  f16* cb16 = (f16*)ws;                              // 12,582,912 B
  f16* x16  = (f16*)(ws + 12582912);                 // 25,165,824 B
  f16* w16  = (f16*)(ws + 12582912 + 25165824);      // 73,728 B

  prep_cb_kernel<<<24576, 256, 0, stream>>>(rpi, mask, rpb, cb16);
  prep_w_kernel<<<144, 256, 0, stream>>>(pw, w16);
  attn_kernel<<<768, 512, 0, stream>>>(qkv, cb16, x16);
  proj_kernel<<<1024, 256, 0, stream>>>(x16, w16, pbv, out);
}